// Round 9
// baseline (4121.432 us; speedup 1.0000x reference)
//
#include <hip/hip_runtime.h>
#include <hip/hip_cooperative_groups.h>
#include <math.h>

namespace cg = cooperative_groups;

#define Bsz 8192
#define NBLK 256                                   // coop-safe grid (1 block/CU)
#define ROT2(x) ((((x) << 2) | ((x) >> 4)) & 63)   // 16-slot granule bank swizzle

typedef __attribute__((ext_vector_type(8))) short short8;   // 8 bf16 = 4 VGPR
typedef __attribute__((ext_vector_type(4))) float float4v;  // MFMA C/D frag

static constexpr float INV_T = 1.0f / 0.07f;  // logit scale; also fixed logsumexp shift

// RNE float->bf16 pack (x -> low16, y -> high16)
static __device__ inline unsigned pack_bf16(float x, float y) {
    union { float f; unsigned u; } a, b;
    a.f = x; b.f = y;
    unsigned ra = a.u + 0x7FFF + ((a.u >> 16) & 1);
    unsigned rb = b.u + 0x7FFF + ((b.u >> 16) & 1);
    return (ra >> 16) | (rb & 0xFFFF0000u);
}

static __device__ inline float dot4(float4 a, float4 b) {
    return a.x*b.x + a.y*b.y + a.z*b.z + a.w*b.w;
}

// ============================================================================
// ONE cooperative kernel: 256 blocks x 512 threads (8 waves), 1 block/CU.
// A: normalize/select 32 rows/block, Yf fragment transpose (2 tiles/block)
// B: prefix over 256 counts -> compacted Xb / pos / orig / flag / lAcc=0
// C: rowblk = pb>>1 (64 shared rows, 128 rowblks); block parity = 256-tile
//    half; each of 8 waves sweeps 32 col-tiles. Full coverage:
//    256 blk x 8 waves x 64 rows x 32 tiles = 8192 x 8192.
// D: finish
// ============================================================================
__global__ __launch_bounds__(512, 2) void fused_kernel(
    const float4* __restrict__ fv4, const float4* __restrict__ fi4,
    const float4* __restrict__ v4,  const float4* __restrict__ vi4,
    uint2* __restrict__ Xb2, uint4* __restrict__ Yf0, uint4* __restrict__ Yf1,
    float* __restrict__ posArr, int* __restrict__ origArr, int* __restrict__ flagArr,
    float* __restrict__ lAcc, float* __restrict__ out, int* __restrict__ cntArr)
{
    __shared__ union {
        struct { unsigned T0[32 * 68]; unsigned T1[32 * 68]; } a;  // A: 17.4 KB
        struct { uint4 Xf[1024]; } c;                              // C: 16 KB shared X tile
    } U;
    __shared__ int sFlagL[32];   // A->B: per-local-row flavor
    __shared__ int sRank[32];    // A->B: rank within flavor
    __shared__ int sW[4];        // B: cross-wave partials
    __shared__ int sFlag[64];    // C: per-compacted-row flavor
    __shared__ int sHas[2];      // C: flavor presence

    const int t    = threadIdx.x;
    const int pb   = blockIdx.x;
    const int wave = t >> 6;
    const int lane = t & 63;
    const int rl   = t >> 4;          // local row 0..31 (16 lanes per row)
    const int sub  = t & 15;
    const int b    = pb * 32 + rl;    // original row
    const int base = b * 32;          // float4 base of row

    // ---------------- phase A ----------------
    const float4 afv0 = fv4[base + sub], afv1 = fv4[base + 16 + sub];
    const float4 afi0 = fi4[base + sub], afi1 = fi4[base + 16 + sub];
    const float4 av0  = v4 [base + sub], av1  = v4 [base + 16 + sub];
    const float4 avi0 = vi4[base + sub], avi1 = vi4[base + 16 + sub];

    float nfv = dot4(afv0, afv0) + dot4(afv1, afv1);
    float nfi = dot4(afi0, afi0) + dot4(afi1, afi1);
    float nv  = dot4(av0,  av0 ) + dot4(av1,  av1 );
    float nvi = dot4(avi0, avi0) + dot4(avi1, avi1);
    float dv  = dot4(afv0, av0 ) + dot4(afv1, av1 );
    float di  = dot4(afi0, avi0) + dot4(afi1, avi1);

    #pragma unroll
    for (int m = 1; m < 16; m <<= 1) {   // 16-lane row-group butterfly
        nfv += __shfl_xor(nfv, m);
        nfi += __shfl_xor(nfi, m);
        nv  += __shfl_xor(nv,  m);
        nvi += __shfl_xor(nvi, m);
        dv  += __shfl_xor(dv,  m);
        di  += __shfl_xor(di,  m);
    }

    const float rnfv = 1.0f / fmaxf(sqrtf(nfv), 1e-12f);
    const float rnfi = 1.0f / fmaxf(sqrtf(nfi), 1e-12f);
    const float rnv  = 1.0f / fmaxf(sqrtf(nv ), 1e-12f);
    const float rnvi = 1.0f / fmaxf(sqrtf(nvi), 1e-12f);

    const float pos_v = dv * rnfv * rnv;
    const float pos_i = di * rnfi * rnvi;
    const bool useV = (pos_v >= pos_i);
    const float pos = useV ? pos_v : pos_i;
    const float sc  = useV ? rnfv : rnfi;
    const int   f   = useV ? 0 : 1;
    const float4 ax0 = useV ? afv0 : afi0;   // live across sync1
    const float4 ax1 = useV ? afv1 : afi1;

    *(uint2*)&U.a.T0[rl * 68 + 2 * sub] =
        make_uint2(pack_bf16(av0.x * rnv, av0.y * rnv), pack_bf16(av0.z * rnv, av0.w * rnv));
    *(uint2*)&U.a.T0[rl * 68 + 32 + 2 * sub] =
        make_uint2(pack_bf16(av1.x * rnv, av1.y * rnv), pack_bf16(av1.z * rnv, av1.w * rnv));
    *(uint2*)&U.a.T1[rl * 68 + 2 * sub] =
        make_uint2(pack_bf16(avi0.x * rnvi, avi0.y * rnvi), pack_bf16(avi0.z * rnvi, avi0.w * rnvi));
    *(uint2*)&U.a.T1[rl * 68 + 32 + 2 * sub] =
        make_uint2(pack_bf16(avi1.x * rnvi, avi1.y * rnvi), pack_bf16(avi1.z * rnvi, avi1.w * rnvi));
    if (sub == 0) sFlagL[rl] = f;
    __syncthreads();

    if (t < 64) {   // wave 0: count store + within-block flavor ranks
        const int ff = (lane < 32) ? sFlagL[lane] : 2;
        const unsigned long long m0 = __ballot(ff == 0);
        const unsigned long long m1 = __ballot(ff == 1);
        if (lane == 0) cntArr[pb] = (int)__popcll(m0);
        if (lane < 32) {
            const unsigned long long below = (1ull << lane) - 1ull;
            sRank[lane] = (ff == 0) ? (int)__popcll(m0 & below) : (int)__popcll(m1 & below);
        }
    }
    // fragment-ordered Yf write: 2 tiles/block, uint4 per thread
    {
        const int tile = t >> 8;                 // 0..1
        const int kc   = (t >> 6) & 3;
        const int lp   = t & 63;
        const int row  = tile * 16 + (lp & 15);
        const int srcw = row * 68 + kc * 16 + (lp >> 4) * 4;
        Yf0[pb * 512 + t] = *(const uint4*)&U.a.T0[srcw];
        Yf1[pb * 512 + t] = *(const uint4*)&U.a.T1[srcw];
    }

    cg::this_grid().sync();   // ---- sync1 ----

    // ---------------- phase B: prefix + compacted writes ----------------
    {
        int vsum = 0;
        if (t < 256 && t < pb) vsum = cntArr[t];
        #pragma unroll
        for (int m = 1; m < 64; m <<= 1) vsum += __shfl_xor(vsum, m);
        if (lane == 0 && wave < 4) sW[wave] = vsum;
        __syncthreads();
        const int S0 = sW[0] + sW[1] + sW[2] + sW[3];   // flavor-0 rows before block

        const int rk = sRank[rl];
        const int p = (f == 0) ? (S0 + rk)
                               : (Bsz - 1 - (32 * pb - S0 + rk));

        Xb2[p * 32 + sub] =
            make_uint2(pack_bf16(ax0.x * sc, ax0.y * sc), pack_bf16(ax0.z * sc, ax0.w * sc));
        Xb2[p * 32 + 16 + sub] =
            make_uint2(pack_bf16(ax1.x * sc, ax1.y * sc), pack_bf16(ax1.z * sc, ax1.w * sc));
        if (sub == 0) {
            posArr[p]  = pos;
            origArr[p] = b;
            flagArr[p] = f;
            lAcc[p]    = 0.0f;
        }
    }

    cg::this_grid().sync();   // ---- sync2 ----

    // ---------------- phase C: MFMA GEMM-row + gated exp-sum ----------------
    const int quad  = lane >> 4;
    const int mrow  = lane & 15;
    const int p0    = (pb >> 1) * 64;              // rowblk 0..127: full coverage
    const int g0    = (pb & 1) * 256 + wave * 32;  // 32 col-tiles per wave

    if (t < 2) sHas[t] = 0;
    __syncthreads();
    if (t < 64) {
        const int ff = flagArr[p0 + t];
        sFlag[t] = ff;
        atomicOr(&sHas[ff], 1);
    }
    // stage shared X tile into fragment order with rot2 bank swizzle
    #pragma unroll
    for (int it = 0; it < 2; ++it) {
        const int i = t + it * 512;
        const int row = i >> 4, ch = i & 15;
        const uint4 val = ((const uint4*)Xb2)[(p0 + row) * 16 + ch];
        const int blk16 = (row >> 4) * 4 + (ch >> 2);
        const int slot  = (ch & 3) * 16 + (row & 15);
        U.c.Xf[blk16 * 64 + ROT2(slot)] = val;
    }
    __syncthreads();

    short8 afr[4][4];
    #pragma unroll
    for (int rt = 0; rt < 4; ++rt)
        #pragma unroll
        for (int kc = 0; kc < 4; ++kc)
            afr[rt][kc] = *(const short8*)&U.c.Xf[(rt * 4 + kc) * 64 + ROT2(lane)];

    unsigned frmask = 0;
    #pragma unroll
    for (int rt = 0; rt < 4; ++rt)
        #pragma unroll
        for (int r = 0; r < 4; ++r)
            frmask |= (unsigned)sFlag[rt * 16 + quad * 4 + r] << (rt * 4 + r);

    float rowsum[4][4] = {};

    for (int phase = 0; phase < 2; ++phase) {
        if (!sHas[phase]) continue;        // flavor-pure rowblk runs one phase
        const uint4* __restrict__ yb = (phase ? Yf1 : Yf0) + (size_t)g0 * 256 + lane;

        float gate[4][4];                  // 1.0 where this lane-row matches phase
        #pragma unroll
        for (int rt = 0; rt < 4; ++rt)
            #pragma unroll
            for (int r = 0; r < 4; ++r)
                gate[rt][r] = ((int)((frmask >> (rt * 4 + r)) & 1u) == phase) ? 1.0f : 0.0f;

        short8 bfr[2][4];
        #pragma unroll
        for (int kc = 0; kc < 4; ++kc)
            bfr[0][kc] = *(const short8*)&yb[kc * 64];

        #pragma unroll 1
        for (int jt = 0; jt < 32; ++jt) {
            const int cur = jt & 1;
            if (jt < 31) {                 // full next-tile register prefetch
                #pragma unroll
                for (int kc = 0; kc < 4; ++kc)
                    bfr[cur ^ 1][kc] = *(const short8*)&yb[256 + kc * 64];
            }

            float4v acc[4] = {};
            #pragma unroll
            for (int kc = 0; kc < 4; ++kc)
                #pragma unroll
                for (int rt = 0; rt < 4; ++rt)
                    acc[rt] = __builtin_amdgcn_mfma_f32_16x16x32_bf16(
                        afr[rt][kc], bfr[cur][kc], acc[rt], 0, 0, 0);
            yb += 256;

            #pragma unroll
            for (int rt = 0; rt < 4; ++rt)
                #pragma unroll
                for (int r = 0; r < 4; ++r) {
                    const float e = __expf(fmaf(acc[rt][r], INV_T, -INV_T));
                    rowsum[rt][r] = fmaf(e, gate[rt][r], rowsum[rt][r]);
                }
        }
    }

    #pragma unroll
    for (int m = 1; m < 16; m <<= 1)
        #pragma unroll
        for (int rt = 0; rt < 4; ++rt)
            #pragma unroll
            for (int r = 0; r < 4; ++r)
                rowsum[rt][r] += __shfl_xor(rowsum[rt][r], m);

    if (mrow == 0) {
        #pragma unroll
        for (int rt = 0; rt < 4; ++rt)
            #pragma unroll
            for (int r = 0; r < 4; ++r)
                atomicAdd(&lAcc[p0 + rt * 16 + quad * 4 + r], rowsum[rt][r]);
    }

    cg::this_grid().sync();   // ---- sync3 ----

    // ---------------- phase D: finish ----------------
    if (t < 32) {
        const int p2 = pb * 32 + t;
        out[origArr[p2]] = logf(lAcc[p2]) + INV_T - posArr[p2] * INV_T;
    }
}

// ---------------- launch ----------------
extern "C" void kernel_launch(void* const* d_in, const int* in_sizes, int n_in,
                              void* d_out, int out_size, void* d_ws, size_t ws_size,
                              hipStream_t stream)
{
    const float4* fv = (const float4*)d_in[0];
    const float4* fi = (const float4*)d_in[1];
    const float4* v  = (const float4*)d_in[2];
    const float4* vi = (const float4*)d_in[3];
    float* out = (float*)d_out;

    unsigned short* XbU  = (unsigned short*)d_ws;    // [B,128] bf16 compacted X
    unsigned short* Yf0U = XbU  + Bsz * 128;         // [B*128] bf16 B-frag-ordered v
    unsigned short* Yf1U = Yf0U + Bsz * 128;         // [B*128] bf16 B-frag-ordered vi
    float* posArr = (float*)(Yf1U + Bsz * 128);      // [B]
    float* lAcc   = posArr + Bsz;                    // [B]
    int*  origArr = (int*)(lAcc + Bsz);              // [B]
    int*  flagArr = origArr + Bsz;                   // [B]
    int*  cntArr  = flagArr + Bsz;                   // [NBLK] per-block flavor-0 counts

    uint2* Xb2 = (uint2*)XbU;
    uint4* Yf0 = (uint4*)Yf0U;
    uint4* Yf1 = (uint4*)Yf1U;

    void* kargs[] = {
        (void*)&fv, (void*)&fi, (void*)&v, (void*)&vi,
        (void*)&Xb2, (void*)&Yf0, (void*)&Yf1,
        (void*)&posArr, (void*)&origArr, (void*)&flagArr,
        (void*)&lAcc, (void*)&out, (void*)&cntArr
    };
    hipLaunchCooperativeKernel((void*)fused_kernel, dim3(NBLK), dim3(512),
                               kargs, 0, stream);
}

// Round 10
// 199.854 us; speedup vs baseline: 20.6222x; 20.6222x over previous
//
#include <hip/hip_runtime.h>
#include <hip/hip_cooperative_groups.h>
#include <math.h>

namespace cg = cooperative_groups;

#define Bsz 8192
#define NBLK 256                                   // coop-safe grid (1 block/CU)
#define ROT2(x) ((((x) << 2) | ((x) >> 4)) & 63)   // 16-slot granule bank swizzle

typedef __attribute__((ext_vector_type(8))) short short8;   // 8 bf16 = 4 VGPR
typedef __attribute__((ext_vector_type(4))) float float4v;  // MFMA C/D frag

static constexpr float INV_T = 1.0f / 0.07f;  // logit scale; also fixed logsumexp shift

// RNE float->bf16 pack (x -> low16, y -> high16)
static __device__ inline unsigned pack_bf16(float x, float y) {
    union { float f; unsigned u; } a, b;
    a.f = x; b.f = y;
    unsigned ra = a.u + 0x7FFF + ((a.u >> 16) & 1);
    unsigned rb = b.u + 0x7FFF + ((b.u >> 16) & 1);
    return (ra >> 16) | (rb & 0xFFFF0000u);
}

static __device__ inline float dot4(float4 a, float4 b) {
    return a.x*b.x + a.y*b.y + a.z*b.z + a.w*b.w;
}

// ============================================================================
// ONE cooperative kernel: 256 blocks x 512 threads (8 waves), 1 block/CU.
// A: normalize/select 32 rows/block, Yf fragment transpose (2 tiles/block)
// B: prefix over 256 counts -> compacted Xb / pos / orig / flag / lAcc=0
// C: rowblk = pb>>1; block parity = 256-tile half; 8 waves x 32 col-tiles.
//    Inner loop: two STATICALLY-NAMED fragment sets (no runtime register
//    indexing -- the R9 bfr[cur] scratch-spill bug), ping-pong prefetch.
// D: finish
// ============================================================================
__global__ __launch_bounds__(512, 2) void fused_kernel(
    const float4* __restrict__ fv4, const float4* __restrict__ fi4,
    const float4* __restrict__ v4,  const float4* __restrict__ vi4,
    uint2* __restrict__ Xb2, uint4* __restrict__ Yf0, uint4* __restrict__ Yf1,
    float* __restrict__ posArr, int* __restrict__ origArr, int* __restrict__ flagArr,
    float* __restrict__ lAcc, float* __restrict__ out, int* __restrict__ cntArr)
{
    __shared__ union {
        struct { unsigned T0[32 * 68]; unsigned T1[32 * 68]; } a;  // A: 17.4 KB
        struct { uint4 Xf[1024]; } c;                              // C: 16 KB shared X tile
    } U;
    __shared__ int sFlagL[32];   // A->B: per-local-row flavor
    __shared__ int sRank[32];    // A->B: rank within flavor
    __shared__ int sW[4];        // B: cross-wave partials
    __shared__ int sFlag[64];    // C: per-compacted-row flavor
    __shared__ int sHas[2];      // C: flavor presence

    const int t    = threadIdx.x;
    const int pb   = blockIdx.x;
    const int wave = t >> 6;
    const int lane = t & 63;
    const int rl   = t >> 4;          // local row 0..31 (16 lanes per row)
    const int sub  = t & 15;
    const int b    = pb * 32 + rl;    // original row
    const int base = b * 32;          // float4 base of row

    // ---------------- phase A ----------------
    const float4 afv0 = fv4[base + sub], afv1 = fv4[base + 16 + sub];
    const float4 afi0 = fi4[base + sub], afi1 = fi4[base + 16 + sub];
    const float4 av0  = v4 [base + sub], av1  = v4 [base + 16 + sub];
    const float4 avi0 = vi4[base + sub], avi1 = vi4[base + 16 + sub];

    float nfv = dot4(afv0, afv0) + dot4(afv1, afv1);
    float nfi = dot4(afi0, afi0) + dot4(afi1, afi1);
    float nv  = dot4(av0,  av0 ) + dot4(av1,  av1 );
    float nvi = dot4(avi0, avi0) + dot4(avi1, avi1);
    float dv  = dot4(afv0, av0 ) + dot4(afv1, av1 );
    float di  = dot4(afi0, avi0) + dot4(afi1, avi1);

    #pragma unroll
    for (int m = 1; m < 16; m <<= 1) {   // 16-lane row-group butterfly
        nfv += __shfl_xor(nfv, m);
        nfi += __shfl_xor(nfi, m);
        nv  += __shfl_xor(nv,  m);
        nvi += __shfl_xor(nvi, m);
        dv  += __shfl_xor(dv,  m);
        di  += __shfl_xor(di,  m);
    }

    const float rnfv = 1.0f / fmaxf(sqrtf(nfv), 1e-12f);
    const float rnfi = 1.0f / fmaxf(sqrtf(nfi), 1e-12f);
    const float rnv  = 1.0f / fmaxf(sqrtf(nv ), 1e-12f);
    const float rnvi = 1.0f / fmaxf(sqrtf(nvi), 1e-12f);

    const float pos_v = dv * rnfv * rnv;
    const float pos_i = di * rnfi * rnvi;
    const bool useV = (pos_v >= pos_i);
    const float pos = useV ? pos_v : pos_i;
    const float sc  = useV ? rnfv : rnfi;
    const int   f   = useV ? 0 : 1;
    const float4 ax0 = useV ? afv0 : afi0;   // live across sync1
    const float4 ax1 = useV ? afv1 : afi1;

    *(uint2*)&U.a.T0[rl * 68 + 2 * sub] =
        make_uint2(pack_bf16(av0.x * rnv, av0.y * rnv), pack_bf16(av0.z * rnv, av0.w * rnv));
    *(uint2*)&U.a.T0[rl * 68 + 32 + 2 * sub] =
        make_uint2(pack_bf16(av1.x * rnv, av1.y * rnv), pack_bf16(av1.z * rnv, av1.w * rnv));
    *(uint2*)&U.a.T1[rl * 68 + 2 * sub] =
        make_uint2(pack_bf16(avi0.x * rnvi, avi0.y * rnvi), pack_bf16(avi0.z * rnvi, avi0.w * rnvi));
    *(uint2*)&U.a.T1[rl * 68 + 32 + 2 * sub] =
        make_uint2(pack_bf16(avi1.x * rnvi, avi1.y * rnvi), pack_bf16(avi1.z * rnvi, avi1.w * rnvi));
    if (sub == 0) sFlagL[rl] = f;
    __syncthreads();

    if (t < 64) {   // wave 0: count store + within-block flavor ranks
        const int ff = (lane < 32) ? sFlagL[lane] : 2;
        const unsigned long long m0 = __ballot(ff == 0);
        const unsigned long long m1 = __ballot(ff == 1);
        if (lane == 0) cntArr[pb] = (int)__popcll(m0);
        if (lane < 32) {
            const unsigned long long below = (1ull << lane) - 1ull;
            sRank[lane] = (ff == 0) ? (int)__popcll(m0 & below) : (int)__popcll(m1 & below);
        }
    }
    // fragment-ordered Yf write: 2 tiles/block, uint4 per thread
    {
        const int tile = t >> 8;                 // 0..1
        const int kc   = (t >> 6) & 3;
        const int lp   = t & 63;
        const int row  = tile * 16 + (lp & 15);
        const int srcw = row * 68 + kc * 16 + (lp >> 4) * 4;
        Yf0[pb * 512 + t] = *(const uint4*)&U.a.T0[srcw];
        Yf1[pb * 512 + t] = *(const uint4*)&U.a.T1[srcw];
    }

    cg::this_grid().sync();   // ---- sync1 ----

    // ---------------- phase B: prefix + compacted writes ----------------
    {
        int vsum = 0;
        if (t < 256 && t < pb) vsum = cntArr[t];
        #pragma unroll
        for (int m = 1; m < 64; m <<= 1) vsum += __shfl_xor(vsum, m);
        if (lane == 0 && wave < 4) sW[wave] = vsum;
        __syncthreads();
        const int S0 = sW[0] + sW[1] + sW[2] + sW[3];   // flavor-0 rows before block

        const int rk = sRank[rl];
        const int p = (f == 0) ? (S0 + rk)
                               : (Bsz - 1 - (32 * pb - S0 + rk));

        Xb2[p * 32 + sub] =
            make_uint2(pack_bf16(ax0.x * sc, ax0.y * sc), pack_bf16(ax0.z * sc, ax0.w * sc));
        Xb2[p * 32 + 16 + sub] =
            make_uint2(pack_bf16(ax1.x * sc, ax1.y * sc), pack_bf16(ax1.z * sc, ax1.w * sc));
        if (sub == 0) {
            posArr[p]  = pos;
            origArr[p] = b;
            flagArr[p] = f;
            lAcc[p]    = 0.0f;
        }
    }

    cg::this_grid().sync();   // ---- sync2 ----

    // ---------------- phase C: MFMA GEMM-row + gated exp-sum ----------------
    const int quad  = lane >> 4;
    const int mrow  = lane & 15;
    const int p0    = (pb >> 1) * 64;              // rowblk 0..127: full coverage
    const int g0    = (pb & 1) * 256 + wave * 32;  // 32 col-tiles per wave

    if (t < 2) sHas[t] = 0;
    __syncthreads();
    if (t < 64) {
        const int ff = flagArr[p0 + t];
        sFlag[t] = ff;
        atomicOr(&sHas[ff], 1);
    }
    // stage shared X tile into fragment order with rot2 bank swizzle
    #pragma unroll
    for (int it = 0; it < 2; ++it) {
        const int i = t + it * 512;
        const int row = i >> 4, ch = i & 15;
        const uint4 val = ((const uint4*)Xb2)[(p0 + row) * 16 + ch];
        const int blk16 = (row >> 4) * 4 + (ch >> 2);
        const int slot  = (ch & 3) * 16 + (row & 15);
        U.c.Xf[blk16 * 64 + ROT2(slot)] = val;
    }
    __syncthreads();

    short8 afr[4][4];
    #pragma unroll
    for (int rt = 0; rt < 4; ++rt)
        #pragma unroll
        for (int kc = 0; kc < 4; ++kc)
            afr[rt][kc] = *(const short8*)&U.c.Xf[(rt * 4 + kc) * 64 + ROT2(lane)];

    unsigned frmask = 0;
    #pragma unroll
    for (int rt = 0; rt < 4; ++rt)
        #pragma unroll
        for (int r = 0; r < 4; ++r)
            frmask |= (unsigned)sFlag[rt * 16 + quad * 4 + r] << (rt * 4 + r);

    float rowsum[4][4] = {};

    for (int phase = 0; phase < 2; ++phase) {
        if (!sHas[phase]) continue;        // flavor-pure rowblk runs one phase
        const uint4* __restrict__ yb = (phase ? Yf1 : Yf0) + (size_t)g0 * 256 + lane;

        float gate[4][4];                  // 1.0 where this lane-row matches phase
        #pragma unroll
        for (int rt = 0; rt < 4; ++rt)
            #pragma unroll
            for (int r = 0; r < 4; ++r)
                gate[rt][r] = ((int)((frmask >> (rt * 4 + r)) & 1u) == phase) ? 1.0f : 0.0f;

        // two statically-named fragment sets -- NO runtime register indexing
        short8 bfrA[4], bfrB[4];
        #pragma unroll
        for (int kc = 0; kc < 4; ++kc)
            bfrA[kc] = *(const short8*)&yb[kc * 64];

        #pragma unroll 1
        for (int jp = 0; jp < 16; ++jp) {   // each jp handles 2 tiles
            // --- even tile: compute bfrA, prefetch next into bfrB ---
            #pragma unroll
            for (int kc = 0; kc < 4; ++kc)
                bfrB[kc] = *(const short8*)&yb[256 + kc * 64];
            {
                float4v acc[4] = {};
                #pragma unroll
                for (int kc = 0; kc < 4; ++kc)
                    #pragma unroll
                    for (int rt = 0; rt < 4; ++rt)
                        acc[rt] = __builtin_amdgcn_mfma_f32_16x16x32_bf16(
                            afr[rt][kc], bfrA[kc], acc[rt], 0, 0, 0);
                #pragma unroll
                for (int rt = 0; rt < 4; ++rt)
                    #pragma unroll
                    for (int r = 0; r < 4; ++r) {
                        const float e = __expf(fmaf(acc[rt][r], INV_T, -INV_T));
                        rowsum[rt][r] = fmaf(e, gate[rt][r], rowsum[rt][r]);
                    }
            }
            yb += 256;

            // --- odd tile: compute bfrB, prefetch next into bfrA ---
            if (jp < 15) {
                #pragma unroll
                for (int kc = 0; kc < 4; ++kc)
                    bfrA[kc] = *(const short8*)&yb[256 + kc * 64];
            }
            {
                float4v acc[4] = {};
                #pragma unroll
                for (int kc = 0; kc < 4; ++kc)
                    #pragma unroll
                    for (int rt = 0; rt < 4; ++rt)
                        acc[rt] = __builtin_amdgcn_mfma_f32_16x16x32_bf16(
                            afr[rt][kc], bfrB[kc], acc[rt], 0, 0, 0);
                #pragma unroll
                for (int rt = 0; rt < 4; ++rt)
                    #pragma unroll
                    for (int r = 0; r < 4; ++r) {
                        const float e = __expf(fmaf(acc[rt][r], INV_T, -INV_T));
                        rowsum[rt][r] = fmaf(e, gate[rt][r], rowsum[rt][r]);
                    }
            }
            yb += 256;
        }
    }

    #pragma unroll
    for (int m = 1; m < 16; m <<= 1)
        #pragma unroll
        for (int rt = 0; rt < 4; ++rt)
            #pragma unroll
            for (int r = 0; r < 4; ++r)
                rowsum[rt][r] += __shfl_xor(rowsum[rt][r], m);

    if (mrow == 0) {
        #pragma unroll
        for (int rt = 0; rt < 4; ++rt)
            #pragma unroll
            for (int r = 0; r < 4; ++r)
                atomicAdd(&lAcc[p0 + rt * 16 + quad * 4 + r], rowsum[rt][r]);
    }

    cg::this_grid().sync();   // ---- sync3 ----

    // ---------------- phase D: finish ----------------
    if (t < 32) {
        const int p2 = pb * 32 + t;
        out[origArr[p2]] = logf(lAcc[p2]) + INV_T - posArr[p2] * INV_T;
    }
}

// ---------------- launch ----------------
extern "C" void kernel_launch(void* const* d_in, const int* in_sizes, int n_in,
                              void* d_out, int out_size, void* d_ws, size_t ws_size,
                              hipStream_t stream)
{
    const float4* fv = (const float4*)d_in[0];
    const float4* fi = (const float4*)d_in[1];
    const float4* v  = (const float4*)d_in[2];
    const float4* vi = (const float4*)d_in[3];
    float* out = (float*)d_out;

    unsigned short* XbU  = (unsigned short*)d_ws;    // [B,128] bf16 compacted X
    unsigned short* Yf0U = XbU  + Bsz * 128;         // [B*128] bf16 B-frag-ordered v
    unsigned short* Yf1U = Yf0U + Bsz * 128;         // [B*128] bf16 B-frag-ordered vi
    float* posArr = (float*)(Yf1U + Bsz * 128);      // [B]
    float* lAcc   = posArr + Bsz;                    // [B]
    int*  origArr = (int*)(lAcc + Bsz);              // [B]
    int*  flagArr = origArr + Bsz;                   // [B]
    int*  cntArr  = flagArr + Bsz;                   // [NBLK] per-block flavor-0 counts

    uint2* Xb2 = (uint2*)XbU;
    uint4* Yf0 = (uint4*)Yf0U;
    uint4* Yf1 = (uint4*)Yf1U;

    void* kargs[] = {
        (void*)&fv, (void*)&fi, (void*)&v, (void*)&vi,
        (void*)&Xb2, (void*)&Yf0, (void*)&Yf1,
        (void*)&posArr, (void*)&origArr, (void*)&flagArr,
        (void*)&lAcc, (void*)&out, (void*)&cntArr
    };
    hipLaunchCooperativeKernel((void*)fused_kernel, dim3(NBLK), dim3(512),
                               kargs, 0, stream);
}